// Round 8
// baseline (37.164 us; speedup 1.0000x reference)
//
#include <hip/hip_runtime.h>
#include <hip/hip_bf16.h>

#define T_LEN 2048
#define D_DIM 128
#define K_DIM 2048
#define M_DIM 8192
#define LOOKUP 101
#define HWIN 50

typedef __attribute__((ext_vector_type(8))) short short8;
typedef __attribute__((ext_vector_type(4))) float f32x4;

static __device__ __forceinline__ unsigned int f2bf(float f) {
  unsigned int u = __float_as_uint(f);
  return (u + 0x7fffu + ((u >> 16) & 1u)) >> 16;  // RNE bf16 bits
}

static __device__ __forceinline__ short8 pack8(float4 lo, float4 hi) {
  uint4 u;
  u.x = f2bf(lo.x) | (f2bf(lo.y) << 16);
  u.y = f2bf(lo.z) | (f2bf(lo.w) << 16);
  u.z = f2bf(hi.x) | (f2bf(hi.y) << 16);
  u.w = f2bf(hi.z) | (f2bf(hi.w) << 16);
  return *(short8*)&u;
}

typedef __attribute__((address_space(3))) unsigned char lds_uchar;
typedef const __attribute__((address_space(1))) unsigned char g_uchar;
static __device__ __forceinline__ void gll16(const void* g, void* l) {
  __builtin_amdgcn_global_load_lds((g_uchar*)g, (lds_uchar*)l, 16, 0, 0);
}

// ---- Kernel 1: W [2048][128] f32 -> Bp fragment-packed bf16 (512 KB) ----
__global__ __launch_bounds__(256) void k_pack(const float* __restrict__ W,
                                              unsigned short* __restrict__ Bp) {
  __shared__ float sw[32][132];
  const int ks = blockIdx.x;  // 0..63
  const int t = threadIdx.x;
  const float* src = W + (size_t)ks * 32 * D_DIM;
#pragma unroll
  for (int j = 0; j < 4; ++j) {
    int idx = t + j * 256;
    int row = idx >> 5, c4 = idx & 31;
    float4 v = *(const float4*)(src + row * D_DIM + c4 * 4);
    *(float4*)&sw[row][c4 * 4] = v;
  }
  __syncthreads();
#pragma unroll
  for (int e = 0; e < 2; ++e) {
    int f = t * 2 + e;
    int ct = f >> 6, l = f & 63;
    int kr = (l >> 4) * 8, col = ct * 16 + (l & 15);
    uint4 o;
    o.x = f2bf(sw[kr + 0][col]) | (f2bf(sw[kr + 1][col]) << 16);
    o.y = f2bf(sw[kr + 2][col]) | (f2bf(sw[kr + 3][col]) << 16);
    o.z = f2bf(sw[kr + 4][col]) | (f2bf(sw[kr + 5][col]) << 16);
    o.w = f2bf(sw[kr + 6][col]) | (f2bf(sw[kr + 7][col]) << 16);
    *(uint4*)(Bp + (((size_t)(ks * 8 + ct) << 6) + l) * 8) = o;
  }
}

// ---- Kernel 2: producer/consumer GEMM ----
// 256 blocks x 512 thr (8 waves), 32 rows/block, K=2048 as 32 chunks of 64.
// Waves 6,7 = producers: stream x chunks into 12-slot LDS ring (8KB/slot) via gll16,
// depth-2 chunk pipeline, flag-release. Waves 0-5 = consumers: chunk c -> wave c%6,
// Bp loads + swizzled ds_read + pack + 16 MFMA/step, acc partials; done-ack for ring reuse.
#define NCH 32
#define RSL 12

__global__ __launch_bounds__(512, 2) void k_gemm(const float* __restrict__ X,
                                                 const unsigned short* __restrict__ Bp,
                                                 const float* __restrict__ bias,
                                                 unsigned short* __restrict__ Pn) {
  __shared__ __align__(16) unsigned char ring[RSL * 8192];  // 96 KB
  __shared__ int flg[NCH];
  __shared__ int dn[NCH];
  const int tid = threadIdx.x;
  const int lane = tid & 63;
  const int wv = tid >> 6;
  const int r0 = blockIdx.x * 32;
  const int l15 = lane & 15;
  const int kg = lane >> 4;

  if (tid < NCH) { flg[tid] = 0; dn[tid] = 0; }
  __syncthreads();
  volatile int* vflg = flg;
  volatile int* vdn = dn;

  f32x4 acc[2][8];
#pragma unroll
  for (int g = 0; g < 2; ++g)
#pragma unroll
    for (int i = 0; i < 8; ++i) acc[g][i] = (f32x4){0.f, 0.f, 0.f, 0.f};

  if (wv >= 6) {
    // ---------------- producer ----------------
    const int p = wv - 6;
    const int li = lane >> 4;   // row within quad
    const int lg = lane & 15;   // byte-granule slot
    auto issue = [&](int c) {
      unsigned char* slot = ring + (c % RSL) * 8192;
#pragma unroll
      for (int i = 0; i < 8; ++i) {
        int r = 4 * i + li;
        int g = lg ^ (r & 7);   // source pre-swizzle; LDS stays linear
        const float* src = X + (size_t)(r0 + r) * K_DIM + c * 64 + g * 4;
        gll16(src, slot + i * 1024);
      }
    };
    issue(p);                    // chunk p in flight (8 loads)
    for (int c = p; c < NCH; c += 2) {
      if (c + 2 < NCH) {
        if (c + 2 >= RSL) {
          while (vdn[c + 2 - RSL] == 0) __builtin_amdgcn_s_sleep(1);
        }
        issue(c + 2);            // 16 outstanding
        asm volatile("s_waitcnt vmcnt(8)" ::: "memory");  // chunk c landed
      } else {
        asm volatile("s_waitcnt vmcnt(0)" ::: "memory");
      }
      if (lane == 0) vflg[c] = 1;
    }
  } else {
    // ---------------- consumer ----------------
    for (int c = wv; c < NCH; c += 6) {
      while (vflg[c] == 0) __builtin_amdgcn_s_sleep(1);
      const unsigned char* slot = ring + (c % RSL) * 8192;
#pragma unroll
      for (int s = 0; s < 2; ++s) {
        short8 wc[8];
        int ksg = c * 2 + s;
#pragma unroll
        for (int ct = 0; ct < 8; ++ct)
          wc[ct] = *(const short8*)(Bp + (((size_t)ksg * 8 + ct) * 64 + lane) * 8);
#pragma unroll
        for (int rg = 0; rg < 2; ++rg) {
          int r = rg * 16 + l15;
          const unsigned char* rb = slot + (r >> 2) * 1024 + (r & 3) * 256;
          int g0 = s * 8 + kg * 2;
          float4 lo = *(const float4*)(rb + ((g0 ^ (r & 7)) << 4));
          float4 hi = *(const float4*)(rb + (((g0 + 1) ^ (r & 7)) << 4));
          short8 xf = pack8(lo, hi);
#pragma unroll
          for (int ct = 0; ct < 8; ++ct)
            acc[rg][ct] = __builtin_amdgcn_mfma_f32_16x16x32_bf16(wc[ct], xf, acc[rg][ct], 0, 0, 0);
        }
      }
      if (lane == 0) vdn[c] = 1;  // DS in-order: issued after the chunk's ds_reads
    }
  }
  __syncthreads();

  // consumers write partial buffers (reuse ring: 6 x 16 KB)
  if (wv < 6) {
    unsigned char* pb = ring + wv * 16384;
#pragma unroll
    for (int rg = 0; rg < 2; ++rg)
#pragma unroll
      for (int ct = 0; ct < 8; ++ct) {
        int byte = (rg * 16 + l15) * 512 + ((ct * 64 + kg * 16) ^ ((l15 & 7) << 4));
        *(float4*)(pb + byte) =
            make_float4(acc[rg][ct][0], acc[rg][ct][1], acc[rg][ct][2], acc[rg][ct][3]);
      }
  }
  __syncthreads();

  // reduce 6 partials + bias + row-normalize + store bf16
  const int row = tid >> 4;   // 0..31
  const int c8 = tid & 15;    // 8 cols each
  float tot[8];
#pragma unroll
  for (int i = 0; i < 8; ++i) tot[i] = 0.f;
#pragma unroll
  for (int q = 0; q < 6; ++q)
#pragma unroll
    for (int h = 0; h < 2; ++h) {
      int byte = q * 16384 + row * 512 + ((c8 * 32 + h * 16) ^ ((row & 7) << 4));
      float4 v = *(const float4*)(ring + byte);
      tot[h * 4 + 0] += v.x; tot[h * 4 + 1] += v.y;
      tot[h * 4 + 2] += v.z; tot[h * 4 + 3] += v.w;
    }
  float4 bv0 = *(const float4*)(bias + c8 * 8);
  float4 bv1 = *(const float4*)(bias + c8 * 8 + 4);
  tot[0] += bv0.x; tot[1] += bv0.y; tot[2] += bv0.z; tot[3] += bv0.w;
  tot[4] += bv1.x; tot[5] += bv1.y; tot[6] += bv1.z; tot[7] += bv1.w;
  float ss = 0.f;
#pragma unroll
  for (int i = 0; i < 8; ++i) ss += tot[i] * tot[i];
  ss += __shfl_xor(ss, 1);
  ss += __shfl_xor(ss, 2);
  ss += __shfl_xor(ss, 4);
  ss += __shfl_xor(ss, 8);
  float sc = 1.0f / fmaxf(sqrtf(ss), 1e-12f);
  uint4 o;
  o.x = f2bf(tot[0] * sc) | (f2bf(tot[1] * sc) << 16);
  o.y = f2bf(tot[2] * sc) | (f2bf(tot[3] * sc) << 16);
  o.z = f2bf(tot[4] * sc) | (f2bf(tot[5] * sc) << 16);
  o.w = f2bf(tot[6] * sc) | (f2bf(tot[7] * sc) << 16);
  *(uint4*)(Pn + (size_t)(r0 + row) * D_DIM + c8 * 8) = o;
}

// ---------------- Kernel 3: banded similarity via MFMA ----------------
#define SROWS 144

__global__ __launch_bounds__(256) void k_sim(const unsigned short* __restrict__ Pn,
                                             float* __restrict__ out) {
  __shared__ unsigned short sm[SROWS * D_DIM];  // 36 KiB, XOR-swizzled 8-short groups
  const int bb = blockIdx.x >> 6;
  const int tb = blockIdx.x & 63;
  const int t0 = tb * 32;
  const int tid = threadIdx.x;

  for (int idx = tid; idx < SROWS * 16; idx += 256) {
    int i = idx >> 4, seg = idx & 15;
    int t = t0 - HWIN + i;
    uint4 val = make_uint4(0u, 0u, 0u, 0u);
    if (t >= 0 && t < T_LEN)
      val = *(const uint4*)(Pn + ((size_t)bb * T_LEN + t) * D_DIM + seg * 8);
    *(uint4*)&sm[i * D_DIM + ((seg ^ (i & 7)) << 3)] = val;
  }
  __syncthreads();

  const int lane = tid & 63;
  const int wv = tid >> 6;
  const int l15 = lane & 15;
  const int kg = lane >> 4;
  const int rt = wv >> 1;
  const int itp = wv & 1;

  short8 af[4];
  const int ia = HWIN + rt * 16 + l15;
#pragma unroll
  for (int ks = 0; ks < 4; ++ks) {
    int g = ks * 4 + kg;
    af[ks] = *(const short8*)&sm[ia * D_DIM + ((g ^ (ia & 7)) << 3)];
  }

  for (int it = itp; it < 9; it += 2) {
    f32x4 acc = (f32x4){0.f, 0.f, 0.f, 0.f};
    const int ib = it * 16 + l15;
#pragma unroll
    for (int ks = 0; ks < 4; ++ks) {
      int g = ks * 4 + kg;
      short8 bf = *(const short8*)&sm[ib * D_DIM + ((g ^ (ib & 7)) << 3)];
      acc = __builtin_amdgcn_mfma_f32_16x16x32_bf16(af[ks], bf, acc, 0, 0, 0);
    }
#pragma unroll
    for (int j = 0; j < 4; ++j) {
      int r = rt * 16 + kg * 4 + j;
      int w = ib - r;
      if (w >= 0 && w <= 100)
        out[((size_t)bb * T_LEN + t0 + r) * LOOKUP + w] = acc[j];
    }
  }
}

extern "C" void kernel_launch(void* const* d_in, const int* in_sizes, int n_in,
                              void* d_out, int out_size, void* d_ws, size_t ws_size,
                              hipStream_t stream) {
  (void)in_sizes; (void)n_in; (void)out_size; (void)ws_size;
  const float* x = (const float*)d_in[0];
  const float* W = (const float*)d_in[1];
  const float* b = (const float*)d_in[2];
  float* out = (float*)d_out;
  unsigned short* Bp = (unsigned short*)d_ws;            // 512 KiB fragment-packed W
  unsigned short* Pn = Bp + (size_t)D_DIM * K_DIM;       // 8192*128 bf16 = 2 MiB

  k_pack<<<64, 256, 0, stream>>>(W, Bp);
  k_gemm<<<M_DIM / 32, 512, 0, stream>>>(x, Bp, b, Pn);
  k_sim<<<4 * (T_LEN / 32), 256, 0, stream>>>(Pn, out);
}